// Round 10
// baseline (377.498 us; speedup 1.0000x reference)
//
#include <hip/hip_runtime.h>

// SNN with "swapped outputs" bug: stored state = spike (binary), forwarded
// value = membrane. reset = (spk_prev > 1) == 0 always -> mem = cur + 0.9*spk_prev.
// Constant input -> spike patterns fixate: mem0 const t>=1, mem1 t>=2, out t>=3.
// GEMM0 (256x2048,K=1024); GEMM1 {mem0(0),mem0(inf)} (M=512,K=2048);
// GEMM2 {mem1(0),mem1(1),mem1(inf)} (M=768,N=1024,K=2048); broadcast t>=3.
//
// Round-10: single fp16 MFMA GEMM (no split). fp16 max error ~0.005
// (empirically scaled from round-5's measured bf16 max 0.039 / 8), SDELTA=0.01
// gives 2x margin; f64 fixup of borderline elements keeps all spike decisions
// within the accuracy envelope that rounds 5-9 verified passing.

typedef _Float16 half_t;
typedef __attribute__((ext_vector_type(8))) _Float16 f16x8;
typedef __attribute__((ext_vector_type(4))) _Float16 h4;
typedef __attribute__((ext_vector_type(4))) float f32x4;

#define SDELTA 0.01f
#define LCAP 65536

__device__ inline float4 ld4(const float* p) { return *reinterpret_cast<const float4*>(p); }
__device__ inline h4 f4h(float4 v) {
    h4 o; o[0] = (half_t)v.x; o[1] = (half_t)v.y; o[2] = (half_t)v.z; o[3] = (half_t)v.w;
    return o;
}

__device__ inline void gload16(const void* g, void* l) {
    __builtin_amdgcn_global_load_lds(
        (__attribute__((address_space(1))) void*)g,
        (__attribute__((address_space(3))) void*)l, 16, 0, 0);
}

// ---- 128x128 split-K GEMM, BK=64, global_load_lds staging (m97 structure) ----
__global__ __launch_bounds__(256) void gemm_splitk(
    const half_t* __restrict__ A,    // [M, K] fp16
    const half_t* __restrict__ W,    // [N, K] fp16
    float* __restrict__ P,           // [S, M, N] f32 partials
    int M, int N, int K, int Kc)
{
    __shared__ half_t As[128 * 64];
    __shared__ half_t Ws[128 * 64];

    const int tid  = threadIdx.x;
    const int lane = tid & 63;
    const int wid  = tid >> 6;
    const int row0 = blockIdx.y * 128;
    const int col0 = blockIdx.x * 128;
    const int k0   = blockIdx.z * Kc;

    const int srow = wid * 32 + (lane >> 3);
    const int scol = (lane & 7) * 8;
    const half_t* Ag = A + (size_t)(row0 + srow) * K + k0 + scol;
    const half_t* Wg = W + (size_t)(col0 + srow) * K + k0 + scol;

    const int wr = wid >> 1, wc = wid & 1;
    const int l15 = lane & 15;
    const int kh  = lane >> 4;
    const half_t* aP = &As[(wr * 64 + l15) * 64 + kh * 8];
    const half_t* bP = &Ws[(wc * 64 + l15) * 64 + kh * 8];

    f32x4 acc[4][4] = {};
    const int NIT = Kc / 64;

    for (int it = 0; it < NIT; ++it) {
        const int kk = it * 64;
#pragma unroll
        for (int i = 0; i < 4; ++i) {
            gload16(Ag + (size_t)(i * 8) * K + kk, &As[(wid * 32 + i * 8) * 64]);
            gload16(Wg + (size_t)(i * 8) * K + kk, &Ws[(wid * 32 + i * 8) * 64]);
        }
        __syncthreads();
#pragma unroll
        for (int ks = 0; ks < 2; ++ks) {
            f16x8 af[4], bf[4];
#pragma unroll
            for (int m = 0; m < 4; ++m)
                af[m] = *reinterpret_cast<const f16x8*>(aP + (m * 16) * 64 + ks * 32);
#pragma unroll
            for (int n = 0; n < 4; ++n)
                bf[n] = *reinterpret_cast<const f16x8*>(bP + (n * 16) * 64 + ks * 32);
#pragma unroll
            for (int m = 0; m < 4; ++m)
#pragma unroll
                for (int n = 0; n < 4; ++n)
                    acc[m][n] = __builtin_amdgcn_mfma_f32_16x16x32_f16(
                        af[m], bf[n], acc[m][n], 0, 0, 0);
        }
        __syncthreads();
    }

    float* Pp = P + ((size_t)blockIdx.z * M + row0) * N + col0;
#pragma unroll
    for (int n = 0; n < 4; ++n) {
        const int col = wc * 64 + n * 16 + l15;
#pragma unroll
        for (int m = 0; m < 4; ++m) {
            const int rb = wr * 64 + m * 16 + kh * 4;
#pragma unroll
            for (int i = 0; i < 4; ++i)
                Pp[(size_t)(rb + i) * N + col] = acc[m][n][i];
        }
    }
}

// ---------------- merged f32->fp16 conversions + counter zeroing ----------------
__global__ __launch_bounds__(256) void cvt_all(
    const float4* __restrict__ x,  const float4* __restrict__ W0,
    const float4* __restrict__ W1, const float4* __restrict__ W2,
    h4* __restrict__ xb,  h4* __restrict__ Wb0,
    h4* __restrict__ Wb1, h4* __restrict__ Wb2,
    int* __restrict__ ctrs)
{
    const int b = blockIdx.x, tid = threadIdx.x;
    if (b == 0 && tid < 3) ctrs[tid * 16] = 0;
    if (b < 256)       { int i = b * 256 + tid;          xb[i]  = f4h(x[i]);  }
    else if (b < 2304) { int i = (b - 256) * 256 + tid;  Wb0[i] = f4h(W0[i]); }
    else if (b < 6400) { int i = (b - 2304) * 256 + tid; Wb1[i] = f4h(W1[i]); }
    else               { int i = (b - 6400) * 256 + tid; Wb2[i] = f4h(W2[i]); }
}

// ---------------- wave compaction of flagged indices ----------------
__device__ inline void emit(const int* loc, int lc, int* list, int* counter)
{
    const int lane = threadIdx.x & 63;
    int inc = lc;
#pragma unroll
    for (int off = 1; off < 64; off <<= 1) {
        int t = __shfl_up(inc, off);
        if (lane >= off) inc += t;
    }
    const int total = __shfl(inc, 63);
    int base = 0;
    if (lane == 63 && total) base = atomicAdd(counter, total);
    base = __shfl(base, 63);
    const int excl = inc - lc;
    for (int j = 0; j < lc; ++j) {
        int p = base + excl + j;
        if (p < LCAP) list[p] = loc[j];
    }
}

__device__ inline int flag4(float4 v, int e0, int* loc, int lc)
{
    float vv[4] = {v.x, v.y, v.z, v.w};
#pragma unroll
    for (int c = 0; c < 4; ++c)
        if ((fabsf(vv[c] - 1.0f) < SDELTA) || (fabsf(vv[c] - 0.1f) < SDELTA))
            loc[lc++] = e0 + c;
    return lc;
}

__device__ inline float4 lifstep(float4 cur, float4 gate)
{
    float4 o;
    o.x = cur.x + ((gate.x > 1.0f) ? 0.9f : 0.0f);
    o.y = cur.y + ((gate.y > 1.0f) ? 0.9f : 0.0f);
    o.z = cur.z + ((gate.z > 1.0f) ? 0.9f : 0.0f);
    o.w = cur.w + ((gate.w > 1.0f) ? 0.9f : 0.0f);
    return o;
}

// ---- layer 0 epilogue: reduce S=8 + bias, scan, C0 write, A1 fp16 ----
__global__ __launch_bounds__(256) void fused0(
    const float4* __restrict__ P, const float* __restrict__ bias,
    float4* __restrict__ C0, half_t* __restrict__ A1b,
    int* __restrict__ list, int* __restrict__ counter)
{
    const int i = blockIdx.x * 256 + threadIdx.x;   // < 131072
    float4 s = P[i];
#pragma unroll
    for (int j = 1; j < 8; ++j) {
        float4 t = P[(size_t)j * 131072 + i];
        s.x += t.x; s.y += t.y; s.z += t.z; s.w += t.w;
    }
    const float4 bv = *reinterpret_cast<const float4*>(bias + ((i * 4) & 2047));
    s.x += bv.x; s.y += bv.y; s.z += bv.z; s.w += bv.w;
    C0[i] = s;
    int loc[4];
    int lc = flag4(s, i * 4, loc, 0);
    emit(loc, lc, list, counter);
    float4 mi = lifstep(s, s);
    const int e0 = i * 4, r = e0 >> 11, k = e0 & 2047;
    *reinterpret_cast<h4*>(A1b + (size_t)r * 2048 + k) = f4h(s);
    *reinterpret_cast<h4*>(A1b + (size_t)(256 + r) * 2048 + k) = f4h(mi);
}

// ---- layer 1 epilogue: reduce S=8 both halves, scan, C1, A2 fp16 ----
__global__ __launch_bounds__(256) void fused1(
    const float4* __restrict__ P, const float* __restrict__ bias,
    float4* __restrict__ C1, half_t* __restrict__ A2b,
    int* __restrict__ list, int* __restrict__ counter)
{
    const int i = blockIdx.x * 256 + threadIdx.x;   // < 131072
    float4 c0 = P[i];
    float4 ci = P[131072 + i];
#pragma unroll
    for (int j = 1; j < 8; ++j) {
        float4 t0 = P[(size_t)j * 262144 + i];
        float4 t1 = P[(size_t)j * 262144 + 131072 + i];
        c0.x += t0.x; c0.y += t0.y; c0.z += t0.z; c0.w += t0.w;
        ci.x += t1.x; ci.y += t1.y; ci.z += t1.z; ci.w += t1.w;
    }
    const float4 bv = *reinterpret_cast<const float4*>(bias + ((i * 4) & 2047));
    c0.x += bv.x; c0.y += bv.y; c0.z += bv.z; c0.w += bv.w;
    ci.x += bv.x; ci.y += bv.y; ci.z += bv.z; ci.w += bv.w;
    C1[i] = c0;
    C1[131072 + i] = ci;
    int loc[8];
    int lc = flag4(c0, i * 4, loc, 0);
    lc = flag4(ci, (131072 + i) * 4, loc, lc);
    emit(loc, lc, list, counter);
    float4 m1 = lifstep(ci, c0);
    float4 m2 = lifstep(ci, m1);
    const int e0 = i * 4, r = e0 >> 11, k = e0 & 2047;
    *reinterpret_cast<h4*>(A2b + (size_t)r * 2048 + k) = f4h(c0);
    *reinterpret_cast<h4*>(A2b + (size_t)(256 + r) * 2048 + k) = f4h(m1);
    *reinterpret_cast<h4*>(A2b + (size_t)(512 + r) * 2048 + k) = f4h(m2);
}

// ---- layer 2 epilogue: reduce S=8 + bias + scan -> C2 ----
__global__ __launch_bounds__(256) void reduce_scan2(
    const float4* __restrict__ P, const float* __restrict__ bias,
    float4* __restrict__ C2, int* __restrict__ list, int* __restrict__ counter)
{
    const int i = blockIdx.x * 256 + threadIdx.x;   // < 196608
    float4 s = P[i];
#pragma unroll
    for (int j = 1; j < 8; ++j) {
        float4 t = P[(size_t)j * 196608 + i];
        s.x += t.x; s.y += t.y; s.z += t.z; s.w += t.w;
    }
    const float4 bv = *reinterpret_cast<const float4*>(bias + ((i * 4) & 1023));
    s.x += bv.x; s.y += bv.y; s.z += bv.z; s.w += bv.w;
    C2[i] = s;
    int loc[4];
    int lc = flag4(s, i * 4, loc, 0);
    emit(loc, lc, list, counter);
}

// ---------------- fixups: exact f64 dots, patch C and A fp16 ----------------
__device__ inline double wred(double p)
{
#pragma unroll
    for (int off = 32; off; off >>= 1) p += __shfl_down(p, off);
    return __shfl(p, 0);
}

__global__ __launch_bounds__(256) void fixup0(
    float* __restrict__ C0, half_t* __restrict__ A1b,
    const float* __restrict__ X, const float* __restrict__ W0,
    const float* __restrict__ b0,
    const int* __restrict__ list, const int* __restrict__ counter)
{
    const int lane = threadIdx.x & 63;
    const int wave = (blockIdx.x * 256 + threadIdx.x) >> 6;
    const int nw = gridDim.x * 4;
    const int nbad = min(*counter, LCAP);
    const int chunk = (nbad + nw - 1) / nw;
    for (int e = wave * chunk; e < min(wave * chunk + chunk, nbad); ++e) {
        const int idx = list[e];
        const int rr = idx >> 11, cc = idx & 2047;
        double p = 0.0;
        for (int k = lane * 4; k < 1024; k += 256) {
            float4 a4 = ld4(X + (size_t)rr * 1024 + k);
            float4 w4 = ld4(W0 + (size_t)cc * 1024 + k);
            p = fma((double)a4.x, (double)w4.x, p);
            p = fma((double)a4.y, (double)w4.y, p);
            p = fma((double)a4.z, (double)w4.z, p);
            p = fma((double)a4.w, (double)w4.w, p);
        }
        const double tot = wred(p);
        if (lane == 0) {
            float c = (float)(tot + (double)b0[cc]);
            C0[idx] = c;
            float mi = c + ((c > 1.0f) ? 0.9f : 0.0f);
            A1b[(size_t)rr * 2048 + cc] = (half_t)c;
            A1b[(size_t)(256 + rr) * 2048 + cc] = (half_t)mi;
        }
    }
}

__global__ __launch_bounds__(256) void fixup1(
    float* __restrict__ C1, half_t* __restrict__ A2b,
    const float* __restrict__ C0, const float* __restrict__ W1,
    const float* __restrict__ b1,
    const int* __restrict__ list, const int* __restrict__ counter)
{
    const int lane = threadIdx.x & 63;
    const int wave = (blockIdx.x * 256 + threadIdx.x) >> 6;
    const int nw = gridDim.x * 4;
    const int nbad = min(*counter, LCAP);
    const int chunk = (nbad + nw - 1) / nw;
    for (int e = wave * chunk; e < min(wave * chunk + chunk, nbad); ++e) {
        const int idx = list[e];
        const int rr = idx >> 11, cc = idx & 2047;
        const int rp = rr & 255;
        double p0 = 0.0, p1 = 0.0;
        for (int k = lane * 4; k < 2048; k += 256) {
            float4 a4 = ld4(C0 + (size_t)rp * 2048 + k);   // mem0(0) row
            float4 w4 = ld4(W1 + (size_t)cc * 2048 + k);
            float4 b4 = lifstep(a4, a4);                    // mem0(inf) row
            p0 = fma((double)a4.x, (double)w4.x, p0);
            p0 = fma((double)a4.y, (double)w4.y, p0);
            p0 = fma((double)a4.z, (double)w4.z, p0);
            p0 = fma((double)a4.w, (double)w4.w, p0);
            p1 = fma((double)b4.x, (double)w4.x, p1);
            p1 = fma((double)b4.y, (double)w4.y, p1);
            p1 = fma((double)b4.z, (double)w4.z, p1);
            p1 = fma((double)b4.w, (double)w4.w, p1);
        }
        const double t0 = wred(p0);
        const double t1 = wred(p1);
        if (lane == 0) {
            float c0 = (float)(t0 + (double)b1[cc]);
            float ci = (float)(t1 + (double)b1[cc]);
            C1[(size_t)rp * 2048 + cc] = c0;
            C1[(size_t)(256 + rp) * 2048 + cc] = ci;
            float m1 = ci + ((c0 > 1.0f) ? 0.9f : 0.0f);
            float m2 = ci + ((m1 > 1.0f) ? 0.9f : 0.0f);
            A2b[(size_t)rp * 2048 + cc] = (half_t)c0;
            A2b[(size_t)(256 + rp) * 2048 + cc] = (half_t)m1;
            A2b[(size_t)(512 + rp) * 2048 + cc] = (half_t)m2;
        }
    }
}

__global__ __launch_bounds__(256) void fixup2(
    float* __restrict__ C2, const float* __restrict__ C1,
    const float* __restrict__ W2, const float* __restrict__ b2,
    const int* __restrict__ list, const int* __restrict__ counter)
{
    const int lane = threadIdx.x & 63;
    const int wave = (blockIdx.x * 256 + threadIdx.x) >> 6;
    const int nw = gridDim.x * 4;
    const int nbad = min(*counter, LCAP);
    const int chunk = (nbad + nw - 1) / nw;
    for (int e = wave * chunk; e < min(wave * chunk + chunk, nbad); ++e) {
        const int idx = list[e];
        const int rr = idx >> 10, cc = idx & 1023;
        const int rp = rr & 255;
        double pA = 0.0, pB = 0.0, pC = 0.0;
        for (int k = lane * 4; k < 2048; k += 256) {
            float4 c04 = ld4(C1 + (size_t)rp * 2048 + k);
            float4 ci4 = ld4(C1 + (size_t)(256 + rp) * 2048 + k);
            float4 w4  = ld4(W2 + (size_t)cc * 2048 + k);
            float4 m14 = lifstep(ci4, c04);
            float4 m24 = lifstep(ci4, m14);
            pA = fma((double)c04.x, (double)w4.x, pA);
            pA = fma((double)c04.y, (double)w4.y, pA);
            pA = fma((double)c04.z, (double)w4.z, pA);
            pA = fma((double)c04.w, (double)w4.w, pA);
            pB = fma((double)m14.x, (double)w4.x, pB);
            pB = fma((double)m14.y, (double)w4.y, pB);
            pB = fma((double)m14.z, (double)w4.z, pB);
            pB = fma((double)m14.w, (double)w4.w, pB);
            pC = fma((double)m24.x, (double)w4.x, pC);
            pC = fma((double)m24.y, (double)w4.y, pC);
            pC = fma((double)m24.z, (double)w4.z, pC);
            pC = fma((double)m24.w, (double)w4.w, pC);
        }
        const double tA = wred(pA);
        const double tB = wred(pB);
        const double tC = wred(pC);
        if (lane == 0) {
            C2[(size_t)rp * 1024 + cc]         = (float)(tA + (double)b2[cc]);
            C2[(size_t)(256 + rp) * 1024 + cc] = (float)(tB + (double)b2[cc]);
            C2[(size_t)(512 + rp) * 1024 + cc] = (float)(tC + (double)b2[cc]);
        }
    }
}

// Final layer + broadcast; grid.y covers 4 time-slices each.
__global__ __launch_bounds__(256) void lif2_bcast(const float4* __restrict__ c2,
                                                  float4* __restrict__ out, int n4)
{
    int i = blockIdx.x * 256 + threadIdx.x;
    if (i >= n4) return;
    float4 c0 = c2[i], c1 = c2[n4 + i], ci = c2[2 * n4 + i];
    float4 m0 = c0;
    float4 m1 = lifstep(c1, m0);
    float4 m2 = lifstep(ci, m1);
    float4 m3 = lifstep(ci, m2);
    int t0 = blockIdx.y * 4;
#pragma unroll
    for (int j = 0; j < 4; ++j) {
        int t = t0 + j;
        float4 v = (t == 0) ? m0 : (t == 1) ? m1 : (t == 2) ? m2 : m3;
        out[(size_t)t * n4 + i] = v;
    }
}

extern "C" void kernel_launch(void* const* d_in, const int* in_sizes, int n_in,
                              void* d_out, int out_size, void* d_ws, size_t ws_size,
                              hipStream_t stream)
{
    const float* x  = (const float*)d_in[0];  // [256,1024]
    const float* W0 = (const float*)d_in[1];  // [2048,1024]
    const float* b0 = (const float*)d_in[2];
    const float* W1 = (const float*)d_in[3];  // [2048,2048]
    const float* b1 = (const float*)d_in[4];
    const float* W2 = (const float*)d_in[5];  // [1024,2048]
    const float* b2 = (const float*)d_in[6];
    float* out = (float*)d_out;
    float* ws  = (float*)d_ws;

    // ws (floats): C0 0.5M | C1 1M | C2 0.75M | ctrs | lists 3x64K
    float* C0 = ws;
    float* C1 = ws + 524288;
    float* C2 = ws + 1572864;
    int* ctrs  = (int*)(ws + 2359296);
    int* list0 = (int*)(ws + 2359360);
    int* list1 = (int*)(ws + 2424896);
    int* list2 = (int*)(ws + 2490432);

    // d_out scratch (ALL overwritten by lif2_bcast at the end):
    half_t* Wb0 = (half_t*)(out);               // [2048,1024] fp16 = 1M floats
    half_t* Wb1 = (half_t*)(out + 1048576);     // [2048,2048] fp16 = 2M floats
    half_t* Wb2 = (half_t*)(out + 3145728);     // [1024,2048] fp16 = 1M floats
    half_t* xb  = (half_t*)(out + 4194304);     // [256,1024]  fp16 = 128K floats
    half_t* A1b = (half_t*)(out + 4325376);     // [512,2048]  fp16 = 512K floats
    half_t* A2b = (half_t*)(out + 4849664);     // [768,2048]  fp16 = 768K floats
    float* Pbuf = out + 5636096;                // split-K partials (max 8.4M floats)

    dim3 blk(256);

    // 1: all fp16 conversions + counter zeroing
    cvt_all<<<dim3(8448), blk, 0, stream>>>((const float4*)x, (const float4*)W0,
                                            (const float4*)W1, (const float4*)W2,
                                            (h4*)xb, (h4*)Wb0, (h4*)Wb1, (h4*)Wb2, ctrs);

    // 2-4: layer 0. GEMM [256,2048] K=1024, S=8 (Kc=128) -> 256 blocks
    gemm_splitk<<<dim3(16, 2, 8), blk, 0, stream>>>(xb, Wb0, Pbuf, 256, 2048, 1024, 128);
    fused0<<<dim3(512), blk, 0, stream>>>((const float4*)Pbuf, b0, (float4*)C0,
                                          A1b, list0, ctrs + 0);
    fixup0<<<dim3(256), blk, 0, stream>>>(C0, A1b, x, W0, b0, list0, ctrs + 0);

    // 5-7: layer 1. GEMM [512,2048] K=2048, S=8 (Kc=256) -> 512 blocks (2/CU)
    gemm_splitk<<<dim3(16, 4, 8), blk, 0, stream>>>(A1b, Wb1, Pbuf, 512, 2048, 2048, 256);
    fused1<<<dim3(512), blk, 0, stream>>>((const float4*)Pbuf, b1, (float4*)C1,
                                          A2b, list1, ctrs + 16);
    fixup1<<<dim3(256), blk, 0, stream>>>(C1, A2b, C0, W1, b1, list1, ctrs + 16);

    // 8-10: layer 2. GEMM [768,1024] K=2048, S=8 (Kc=256) -> 384 blocks
    gemm_splitk<<<dim3(8, 6, 8), blk, 0, stream>>>(A2b, Wb2, Pbuf, 768, 1024, 2048, 256);
    reduce_scan2<<<dim3(768), blk, 0, stream>>>((const float4*)Pbuf, b2, (float4*)C2,
                                                list2, ctrs + 32);
    fixup2<<<dim3(256), blk, 0, stream>>>(C2, C1, W2, b2, list2, ctrs + 32);

    // 11: layer-2 LIF chain + output broadcast (overwrites all of d_out)
    lif2_bcast<<<dim3(256, 25), blk, 0, stream>>>((const float4*)C2, (float4*)out, 65536);
}

// Round 11
// 201.772 us; speedup vs baseline: 1.8709x; 1.8709x over previous
//
#include <hip/hip_runtime.h>

// SNN with "swapped outputs" bug: stored state = spike (binary), forwarded
// value = membrane. reset = (spk_prev > 1) == 0 always -> mem = cur + 0.9*spk_prev.
// Constant input -> spike patterns fixate: mem0 const t>=1, mem1 t>=2, out t>=3.
// GEMM0 (256x2048,K=1024); GEMM1 {mem0(0),mem0(inf)} (M=512,K=2048);
// GEMM2 {mem1(0),mem1(1),mem1(inf)} (M=768,N=1024,K=2048); broadcast t>=3.
// Split-bf16: A=Ah+Al, W=Wh+Wl; Ah.Wh + Ah.Wl + Al.Wh as one logical K'=3K GEMM.
// f64 fixup of elements within SDELTA=1e-3 of decision points -> exact decisions.
//
// Round-10 lesson: plain fp16 tail error reaches >=0.01 -> a layer-1 spike
// decision flipped (absmax 0.0234 ~= 0.9*w2max). Split-bf16 (error ~1e-5) is
// the safe config. Round 11 = round-9 numerics with: [h|l] de-duplicated split
// storage (segment offset mapping, Kc seg-aligned), S=12 split-K fill
// (384/768/576 blocks), XCD-chunked block swizzle for L2 locality.

typedef unsigned short ushort_t;
typedef __attribute__((ext_vector_type(8))) short bf16x8;
typedef __attribute__((ext_vector_type(4))) float f32x4;

#define SDELTA 1.0e-3f
#define LCAP 65536

__device__ inline ushort_t f2bf(float f) {       // RNE f32 -> bf16
    unsigned u = __float_as_uint(f);
    u += 0x7FFFu + ((u >> 16) & 1u);
    return (ushort_t)(u >> 16);
}
__device__ inline float bf2f(ushort_t h) { return __uint_as_float((unsigned)h << 16); }
__device__ inline float4 ld4(const float* p) { return *reinterpret_cast<const float4*>(p); }

__device__ inline void gload16(const void* g, void* l) {
    __builtin_amdgcn_global_load_lds(
        (__attribute__((address_space(1))) void*)g,
        (__attribute__((address_space(3))) void*)l, 16, 0, 0);
}

// ---- 128x128 split-K GEMM over logical K'=3K, physical [h|l] storage ----
// 1D grid nwg = nx*ny*12 (nwg%8==0); XCD-chunked swizzle; Kc segment-aligned.
__global__ __launch_bounds__(256) void gemm_splitk(
    const ushort_t* __restrict__ A,   // [M, 2K] bf16: [Ah|Al]
    const ushort_t* __restrict__ W,   // [N, 2K] bf16: [Wh|Wl]
    float* __restrict__ P,            // [S, M, N] f32 partials
    int M, int N, int K, int Kc, int nx, int ny)
{
    __shared__ ushort_t As[128 * 64];
    __shared__ ushort_t Ws[128 * 64];

    // bijective XCD swizzle: XCD i gets contiguous chunk [i*nwg/8,(i+1)*nwg/8)
    const int nwg = gridDim.x;
    const int lin = blockIdx.x;
    const int swz = (lin & 7) * (nwg >> 3) + (lin >> 3);
    const int nxy = nx * ny;
    const int bz  = swz / nxy;
    const int rem = swz - bz * nxy;
    const int by  = rem / nx;
    const int bx  = rem - by * nx;

    const int tid  = threadIdx.x;
    const int lane = tid & 63;
    const int wid  = tid >> 6;
    const int row0 = by * 128;
    const int col0 = bx * 128;
    const int k0   = bz * Kc;          // logical k in [0, 3K)
    const int st   = 2 * K;            // physical row stride
    // logical segs: A = [h, h, l]; W = [h, l, h]
    const int aoff = (k0 < K) ? k0 : (k0 - K);
    const int woff = (k0 < 2 * K) ? k0 : (k0 - 2 * K);

    const int srow = wid * 32 + (lane >> 3);
    const int scol = (lane & 7) * 8;
    const ushort_t* Ag = A + (size_t)(row0 + srow) * st + aoff + scol;
    const ushort_t* Wg = W + (size_t)(col0 + srow) * st + woff + scol;

    const int wr = wid >> 1, wc = wid & 1;
    const int l15 = lane & 15;
    const int kh  = lane >> 4;
    const ushort_t* aP = &As[(wr * 64 + l15) * 64 + kh * 8];
    const ushort_t* bP = &Ws[(wc * 64 + l15) * 64 + kh * 8];

    f32x4 acc[4][4] = {};
    const int NIT = Kc / 64;

    for (int it = 0; it < NIT; ++it) {
        const int kk = it * 64;
#pragma unroll
        for (int i = 0; i < 4; ++i) {
            gload16(Ag + (size_t)(i * 8) * st + kk, &As[(wid * 32 + i * 8) * 64]);
            gload16(Wg + (size_t)(i * 8) * st + kk, &Ws[(wid * 32 + i * 8) * 64]);
        }
        __syncthreads();
#pragma unroll
        for (int ks = 0; ks < 2; ++ks) {
            bf16x8 af[4], bf[4];
#pragma unroll
            for (int m = 0; m < 4; ++m)
                af[m] = *reinterpret_cast<const bf16x8*>(aP + (m * 16) * 64 + ks * 32);
#pragma unroll
            for (int n = 0; n < 4; ++n)
                bf[n] = *reinterpret_cast<const bf16x8*>(bP + (n * 16) * 64 + ks * 32);
#pragma unroll
            for (int m = 0; m < 4; ++m)
#pragma unroll
                for (int n = 0; n < 4; ++n)
                    acc[m][n] = __builtin_amdgcn_mfma_f32_16x16x32_bf16(
                        af[m], bf[n], acc[m][n], 0, 0, 0);
        }
        __syncthreads();
    }

    float* Pp = P + ((size_t)bz * M + row0) * N + col0;
#pragma unroll
    for (int n = 0; n < 4; ++n) {
        const int col = wc * 64 + n * 16 + l15;
#pragma unroll
        for (int m = 0; m < 4; ++m) {
            const int rb = wr * 64 + m * 16 + kh * 4;
#pragma unroll
            for (int i = 0; i < 4; ++i)
                Pp[(size_t)(rb + i) * N + col] = acc[m][n][i];
        }
    }
}

// ---------------- merged split-conversions ([h|l], width 2K) + ctr zero ----------------
__device__ inline void do_split(const float4* src, ushort_t* dst, int i, int logK)
{
    float4 v = src[i];
    const int K = 1 << logK;
    const int e0 = i * 4;
    const int r = e0 >> logK, k = e0 & (K - 1);
    ushort_t* row = dst + (size_t)r * 2 * K;
    ushort4 h, l;
    h.x = f2bf(v.x); l.x = f2bf(v.x - bf2f(h.x));
    h.y = f2bf(v.y); l.y = f2bf(v.y - bf2f(h.y));
    h.z = f2bf(v.z); l.z = f2bf(v.z - bf2f(h.z));
    h.w = f2bf(v.w); l.w = f2bf(v.w - bf2f(h.w));
    *reinterpret_cast<ushort4*>(row + k) = h;
    *reinterpret_cast<ushort4*>(row + K + k) = l;
}

__global__ __launch_bounds__(256) void cvt_all(
    const float4* __restrict__ x,  const float4* __restrict__ W0,
    const float4* __restrict__ W1, const float4* __restrict__ W2,
    ushort_t* __restrict__ xb,  ushort_t* __restrict__ Wb0,
    ushort_t* __restrict__ Wb1, ushort_t* __restrict__ Wb2,
    int* __restrict__ ctrs)
{
    const int b = blockIdx.x, tid = threadIdx.x;
    if (b == 0 && tid < 3) ctrs[tid * 16] = 0;
    if (b < 256)        do_split(x,  xb,  b * 256 + tid,          10);
    else if (b < 2304)  do_split(W0, Wb0, (b - 256) * 256 + tid,  10);
    else if (b < 6400)  do_split(W1, Wb1, (b - 2304) * 256 + tid, 11);
    else                do_split(W2, Wb2, (b - 6400) * 256 + tid, 11);
}

// ---------------- wave compaction of flagged indices ----------------
__device__ inline void emit(const int* loc, int lc, int* list, int* counter)
{
    const int lane = threadIdx.x & 63;
    int inc = lc;
#pragma unroll
    for (int off = 1; off < 64; off <<= 1) {
        int t = __shfl_up(inc, off);
        if (lane >= off) inc += t;
    }
    const int total = __shfl(inc, 63);
    int base = 0;
    if (lane == 63 && total) base = atomicAdd(counter, total);
    base = __shfl(base, 63);
    const int excl = inc - lc;
    for (int j = 0; j < lc; ++j) {
        int p = base + excl + j;
        if (p < LCAP) list[p] = loc[j];
    }
}

__device__ inline int flag4(float4 v, int e0, int* loc, int lc)
{
    float vv[4] = {v.x, v.y, v.z, v.w};
#pragma unroll
    for (int c = 0; c < 4; ++c)
        if ((fabsf(vv[c] - 1.0f) < SDELTA) || (fabsf(vv[c] - 0.1f) < SDELTA))
            loc[lc++] = e0 + c;
    return lc;
}

__device__ inline void wsplit2(ushort_t* row, int k, float4 v)   // [h|l], width 4096
{
    ushort4 h, l;
    h.x = f2bf(v.x); l.x = f2bf(v.x - bf2f(h.x));
    h.y = f2bf(v.y); l.y = f2bf(v.y - bf2f(h.y));
    h.z = f2bf(v.z); l.z = f2bf(v.z - bf2f(h.z));
    h.w = f2bf(v.w); l.w = f2bf(v.w - bf2f(h.w));
    *reinterpret_cast<ushort4*>(row + k) = h;
    *reinterpret_cast<ushort4*>(row + 2048 + k) = l;
}

__device__ inline float4 lifstep(float4 cur, float4 gate)
{
    float4 o;
    o.x = cur.x + ((gate.x > 1.0f) ? 0.9f : 0.0f);
    o.y = cur.y + ((gate.y > 1.0f) ? 0.9f : 0.0f);
    o.z = cur.z + ((gate.z > 1.0f) ? 0.9f : 0.0f);
    o.w = cur.w + ((gate.w > 1.0f) ? 0.9f : 0.0f);
    return o;
}

// ---- layer 0 epilogue: reduce S=12 + bias, scan, C0 write, A1 [h|l] ----
__global__ __launch_bounds__(256) void fused0(
    const float4* __restrict__ P, const float* __restrict__ bias,
    float4* __restrict__ C0, ushort_t* __restrict__ A1b,
    int* __restrict__ list, int* __restrict__ counter)
{
    const int i = blockIdx.x * 256 + threadIdx.x;   // < 131072
    float4 s = P[i];
#pragma unroll
    for (int j = 1; j < 12; ++j) {
        float4 t = P[(size_t)j * 131072 + i];
        s.x += t.x; s.y += t.y; s.z += t.z; s.w += t.w;
    }
    const float4 bv = *reinterpret_cast<const float4*>(bias + ((i * 4) & 2047));
    s.x += bv.x; s.y += bv.y; s.z += bv.z; s.w += bv.w;
    C0[i] = s;
    int loc[4];
    int lc = flag4(s, i * 4, loc, 0);
    emit(loc, lc, list, counter);
    float4 mi = lifstep(s, s);
    const int e0 = i * 4, r = e0 >> 11, k = e0 & 2047;
    wsplit2(A1b + (size_t)r * 4096, k, s);
    wsplit2(A1b + (size_t)(256 + r) * 4096, k, mi);
}

// ---- layer 1 epilogue: reduce S=12 both halves, scan, C1, A2 [h|l] ----
__global__ __launch_bounds__(256) void fused1(
    const float4* __restrict__ P, const float* __restrict__ bias,
    float4* __restrict__ C1, ushort_t* __restrict__ A2b,
    int* __restrict__ list, int* __restrict__ counter)
{
    const int i = blockIdx.x * 256 + threadIdx.x;   // < 131072
    float4 c0 = P[i];
    float4 ci = P[131072 + i];
#pragma unroll
    for (int j = 1; j < 12; ++j) {
        float4 t0 = P[(size_t)j * 262144 + i];
        float4 t1 = P[(size_t)j * 262144 + 131072 + i];
        c0.x += t0.x; c0.y += t0.y; c0.z += t0.z; c0.w += t0.w;
        ci.x += t1.x; ci.y += t1.y; ci.z += t1.z; ci.w += t1.w;
    }
    const float4 bv = *reinterpret_cast<const float4*>(bias + ((i * 4) & 2047));
    c0.x += bv.x; c0.y += bv.y; c0.z += bv.z; c0.w += bv.w;
    ci.x += bv.x; ci.y += bv.y; ci.z += bv.z; ci.w += bv.w;
    C1[i] = c0;
    C1[131072 + i] = ci;
    int loc[8];
    int lc = flag4(c0, i * 4, loc, 0);
    lc = flag4(ci, (131072 + i) * 4, loc, lc);
    emit(loc, lc, list, counter);
    float4 m1 = lifstep(ci, c0);
    float4 m2 = lifstep(ci, m1);
    const int e0 = i * 4, r = e0 >> 11, k = e0 & 2047;
    wsplit2(A2b + (size_t)r * 4096, k, c0);
    wsplit2(A2b + (size_t)(256 + r) * 4096, k, m1);
    wsplit2(A2b + (size_t)(512 + r) * 4096, k, m2);
}

// ---- layer 2 epilogue: reduce S=12 + bias + scan -> C2 ----
__global__ __launch_bounds__(256) void reduce_scan2(
    const float4* __restrict__ P, const float* __restrict__ bias,
    float4* __restrict__ C2, int* __restrict__ list, int* __restrict__ counter)
{
    const int i = blockIdx.x * 256 + threadIdx.x;   // < 196608
    float4 s = P[i];
#pragma unroll
    for (int j = 1; j < 12; ++j) {
        float4 t = P[(size_t)j * 196608 + i];
        s.x += t.x; s.y += t.y; s.z += t.z; s.w += t.w;
    }
    const float4 bv = *reinterpret_cast<const float4*>(bias + ((i * 4) & 1023));
    s.x += bv.x; s.y += bv.y; s.z += bv.z; s.w += bv.w;
    C2[i] = s;
    int loc[4];
    int lc = flag4(s, i * 4, loc, 0);
    emit(loc, lc, list, counter);
}

// ---------------- fixups: exact f64 dots, patch C and A [h|l] ----------------
__device__ inline void patch2(ushort_t* row, int c, float v)
{
    ushort_t h = f2bf(v);
    ushort_t l = f2bf(v - bf2f(h));
    row[c] = h; row[2048 + c] = l;
}
__device__ inline double wred(double p)
{
#pragma unroll
    for (int off = 32; off; off >>= 1) p += __shfl_down(p, off);
    return __shfl(p, 0);
}

__global__ __launch_bounds__(256) void fixup0(
    float* __restrict__ C0, ushort_t* __restrict__ A1b,
    const float* __restrict__ X, const float* __restrict__ W0,
    const float* __restrict__ b0,
    const int* __restrict__ list, const int* __restrict__ counter)
{
    const int lane = threadIdx.x & 63;
    const int wave = (blockIdx.x * 256 + threadIdx.x) >> 6;
    const int nw = gridDim.x * 4;
    const int nbad = min(*counter, LCAP);
    const int chunk = (nbad + nw - 1) / nw;
    for (int e = wave * chunk; e < min(wave * chunk + chunk, nbad); ++e) {
        const int idx = list[e];
        const int rr = idx >> 11, cc = idx & 2047;
        double p = 0.0;
        for (int k = lane * 4; k < 1024; k += 256) {
            float4 a4 = ld4(X + (size_t)rr * 1024 + k);
            float4 w4 = ld4(W0 + (size_t)cc * 1024 + k);
            p = fma((double)a4.x, (double)w4.x, p);
            p = fma((double)a4.y, (double)w4.y, p);
            p = fma((double)a4.z, (double)w4.z, p);
            p = fma((double)a4.w, (double)w4.w, p);
        }
        const double tot = wred(p);
        if (lane == 0) {
            float c = (float)(tot + (double)b0[cc]);
            C0[idx] = c;
            float mi = c + ((c > 1.0f) ? 0.9f : 0.0f);
            patch2(A1b + (size_t)rr * 4096, cc, c);
            patch2(A1b + (size_t)(256 + rr) * 4096, cc, mi);
        }
    }
}

__global__ __launch_bounds__(256) void fixup1(
    float* __restrict__ C1, ushort_t* __restrict__ A2b,
    const float* __restrict__ C0, const float* __restrict__ W1,
    const float* __restrict__ b1,
    const int* __restrict__ list, const int* __restrict__ counter)
{
    const int lane = threadIdx.x & 63;
    const int wave = (blockIdx.x * 256 + threadIdx.x) >> 6;
    const int nw = gridDim.x * 4;
    const int nbad = min(*counter, LCAP);
    const int chunk = (nbad + nw - 1) / nw;
    for (int e = wave * chunk; e < min(wave * chunk + chunk, nbad); ++e) {
        const int idx = list[e];
        const int rr = idx >> 11, cc = idx & 2047;
        const int rp = rr & 255;
        double p0 = 0.0, p1 = 0.0;
        for (int k = lane * 4; k < 2048; k += 256) {
            float4 a4 = ld4(C0 + (size_t)rp * 2048 + k);   // mem0(0) row
            float4 w4 = ld4(W1 + (size_t)cc * 2048 + k);
            float4 b4 = lifstep(a4, a4);                    // mem0(inf) row
            p0 = fma((double)a4.x, (double)w4.x, p0);
            p0 = fma((double)a4.y, (double)w4.y, p0);
            p0 = fma((double)a4.z, (double)w4.z, p0);
            p0 = fma((double)a4.w, (double)w4.w, p0);
            p1 = fma((double)b4.x, (double)w4.x, p1);
            p1 = fma((double)b4.y, (double)w4.y, p1);
            p1 = fma((double)b4.z, (double)w4.z, p1);
            p1 = fma((double)b4.w, (double)w4.w, p1);
        }
        const double t0 = wred(p0);
        const double t1 = wred(p1);
        if (lane == 0) {
            float c0 = (float)(t0 + (double)b1[cc]);
            float ci = (float)(t1 + (double)b1[cc]);
            C1[(size_t)rp * 2048 + cc] = c0;
            C1[(size_t)(256 + rp) * 2048 + cc] = ci;
            float m1 = ci + ((c0 > 1.0f) ? 0.9f : 0.0f);
            float m2 = ci + ((m1 > 1.0f) ? 0.9f : 0.0f);
            patch2(A2b + (size_t)rp * 4096, cc, c0);
            patch2(A2b + (size_t)(256 + rp) * 4096, cc, m1);
            patch2(A2b + (size_t)(512 + rp) * 4096, cc, m2);
        }
    }
}

__global__ __launch_bounds__(256) void fixup2(
    float* __restrict__ C2, const float* __restrict__ C1,
    const float* __restrict__ W2, const float* __restrict__ b2,
    const int* __restrict__ list, const int* __restrict__ counter)
{
    const int lane = threadIdx.x & 63;
    const int wave = (blockIdx.x * 256 + threadIdx.x) >> 6;
    const int nw = gridDim.x * 4;
    const int nbad = min(*counter, LCAP);
    const int chunk = (nbad + nw - 1) / nw;
    for (int e = wave * chunk; e < min(wave * chunk + chunk, nbad); ++e) {
        const int idx = list[e];
        const int rr = idx >> 10, cc = idx & 1023;
        const int rp = rr & 255;
        double pA = 0.0, pB = 0.0, pC = 0.0;
        for (int k = lane * 4; k < 2048; k += 256) {
            float4 c04 = ld4(C1 + (size_t)rp * 2048 + k);
            float4 ci4 = ld4(C1 + (size_t)(256 + rp) * 2048 + k);
            float4 w4  = ld4(W2 + (size_t)cc * 2048 + k);
            float4 m14 = lifstep(ci4, c04);
            float4 m24 = lifstep(ci4, m14);
            pA = fma((double)c04.x, (double)w4.x, pA);
            pA = fma((double)c04.y, (double)w4.y, pA);
            pA = fma((double)c04.z, (double)w4.z, pA);
            pA = fma((double)c04.w, (double)w4.w, pA);
            pB = fma((double)m14.x, (double)w4.x, pB);
            pB = fma((double)m14.y, (double)w4.y, pB);
            pB = fma((double)m14.z, (double)w4.z, pB);
            pB = fma((double)m14.w, (double)w4.w, pB);
            pC = fma((double)m24.x, (double)w4.x, pC);
            pC = fma((double)m24.y, (double)w4.y, pC);
            pC = fma((double)m24.z, (double)w4.z, pC);
            pC = fma((double)m24.w, (double)w4.w, pC);
        }
        const double tA = wred(pA);
        const double tB = wred(pB);
        const double tC = wred(pC);
        if (lane == 0) {
            C2[(size_t)rp * 1024 + cc]         = (float)(tA + (double)b2[cc]);
            C2[(size_t)(256 + rp) * 1024 + cc] = (float)(tB + (double)b2[cc]);
            C2[(size_t)(512 + rp) * 1024 + cc] = (float)(tC + (double)b2[cc]);
        }
    }
}

// Final layer + broadcast; grid.y covers 4 time-slices each.
__global__ __launch_bounds__(256) void lif2_bcast(const float4* __restrict__ c2,
                                                  float4* __restrict__ out, int n4)
{
    int i = blockIdx.x * 256 + threadIdx.x;
    if (i >= n4) return;
    float4 c0 = c2[i], c1 = c2[n4 + i], ci = c2[2 * n4 + i];
    float4 m0 = c0;
    float4 m1 = lifstep(c1, m0);
    float4 m2 = lifstep(ci, m1);
    float4 m3 = lifstep(ci, m2);
    int t0 = blockIdx.y * 4;
#pragma unroll
    for (int j = 0; j < 4; ++j) {
        int t = t0 + j;
        float4 v = (t == 0) ? m0 : (t == 1) ? m1 : (t == 2) ? m2 : m3;
        out[(size_t)t * n4 + i] = v;
    }
}

extern "C" void kernel_launch(void* const* d_in, const int* in_sizes, int n_in,
                              void* d_out, int out_size, void* d_ws, size_t ws_size,
                              hipStream_t stream)
{
    const float* x  = (const float*)d_in[0];  // [256,1024]
    const float* W0 = (const float*)d_in[1];  // [2048,1024]
    const float* b0 = (const float*)d_in[2];
    const float* W1 = (const float*)d_in[3];  // [2048,2048]
    const float* b1 = (const float*)d_in[4];
    const float* W2 = (const float*)d_in[5];  // [1024,2048]
    const float* b2 = (const float*)d_in[6];
    float* out = (float*)d_out;
    float* ws  = (float*)d_ws;

    // ws (floats): C0 0.5M | C1 1M | C2 0.75M | ctrs | lists 3x64K
    float* C0 = ws;
    float* C1 = ws + 524288;
    float* C2 = ws + 1572864;
    int* ctrs  = (int*)(ws + 2359296);
    int* list0 = (int*)(ws + 2359360);
    int* list1 = (int*)(ws + 2424896);
    int* list2 = (int*)(ws + 2490432);

    // d_out scratch (ALL overwritten by lif2_bcast at the end), float offsets:
    ushort_t* Wb0 = (ushort_t*)(out);               // [2048,2048] bf16 = 2M floats
    ushort_t* Wb1 = (ushort_t*)(out + 2097152);     // [2048,4096] bf16 = 4M floats
    ushort_t* Wb2 = (ushort_t*)(out + 6291456);     // [1024,4096] bf16 = 2M floats
    ushort_t* xb  = (ushort_t*)(out + 8388608);     // [256,2048]  bf16 = 256K floats
    ushort_t* A1b = (ushort_t*)(out + 8650752);     // [512,4096]  bf16 = 1M floats
    ushort_t* A2b = (ushort_t*)(out + 9699328);     // [768,4096]  bf16 = 1.5M floats
    float* Pbuf   = out + 11272192;                 // partials, max 12.6M -> 23.9M < 26.2M

    dim3 blk(256);

    // 1: all split-conversions ([h|l]) + counter zeroing
    cvt_all<<<dim3(8448), blk, 0, stream>>>((const float4*)x, (const float4*)W0,
                                            (const float4*)W1, (const float4*)W2,
                                            xb, Wb0, Wb1, Wb2, ctrs);

    // 2-4: layer 0. K'=3072, Kc=256 (seg-aligned), S=12 -> 16x2x12 = 384 blocks
    gemm_splitk<<<dim3(384), blk, 0, stream>>>(xb, Wb0, Pbuf, 256, 2048, 1024, 256, 16, 2);
    fused0<<<dim3(512), blk, 0, stream>>>((const float4*)Pbuf, b0, (float4*)C0,
                                          A1b, list0, ctrs + 0);
    fixup0<<<dim3(256), blk, 0, stream>>>(C0, A1b, x, W0, b0, list0, ctrs + 0);

    // 5-7: layer 1. K'=6144, Kc=512, S=12 -> 16x4x12 = 768 blocks (3/CU)
    gemm_splitk<<<dim3(768), blk, 0, stream>>>(A1b, Wb1, Pbuf, 512, 2048, 2048, 512, 16, 4);
    fused1<<<dim3(512), blk, 0, stream>>>((const float4*)Pbuf, b1, (float4*)C1,
                                          A2b, list1, ctrs + 16);
    fixup1<<<dim3(256), blk, 0, stream>>>(C1, A2b, C0, W1, b1, list1, ctrs + 16);

    // 8-10: layer 2. K'=6144, Kc=512, S=12 -> 8x6x12 = 576 blocks
    gemm_splitk<<<dim3(576), blk, 0, stream>>>(A2b, Wb2, Pbuf, 768, 1024, 2048, 512, 8, 6);
    reduce_scan2<<<dim3(768), blk, 0, stream>>>((const float4*)Pbuf, b2, (float4*)C2,
                                                list2, ctrs + 32);
    fixup2<<<dim3(256), blk, 0, stream>>>(C2, C1, W2, b2, list2, ctrs + 32);

    // 11: layer-2 LIF chain + output broadcast (overwrites all of d_out)
    lif2_bcast<<<dim3(256, 25), blk, 0, stream>>>((const float4*)C2, (float4*)out, 65536);
}